// Round 1
// baseline (1803.426 us; speedup 1.0000x reference)
//
#include <hip/hip_runtime.h>

#define N_NODES 100000
#define N_EDGES 1250000
#define D_IN 64
#define D_H 64
#define D_OUT 32

// Workspace layout (floats):
//   deg   [N]          : in-degree (as float)
//   agg1  [N*64]       : sum_{j in N(i)} x_j
//   agg2  [N*32]       : sum_{j in N(i)} hWl_j
//   hWl   [N*32]       : h @ W2_l^T   (pre-multiplied so layer-2 aggregates in 32 dims)
//   hr    [N*32]       : h @ W2_r^T   (root term of layer 2)
// total 161*N floats = 64.4 MB

__global__ void k_deg(const int* __restrict__ dst, float* __restrict__ deg) {
    int e = blockIdx.x * blockDim.x + threadIdx.x;
    if (e < N_EDGES) {
        int d = dst[e];
        if ((unsigned)d < N_NODES) atomicAdd(&deg[d], 1.0f);
    }
}

// 16 threads per edge, each handles one float4 of the 64-dim row.
__global__ void k_scatter1(const int* __restrict__ src, const int* __restrict__ dst,
                           const float* __restrict__ x, float* __restrict__ agg1) {
    long long t = (long long)blockIdx.x * blockDim.x + threadIdx.x;
    if (t >= (long long)N_EDGES * 16) return;
    int e = (int)(t >> 4);
    int q = ((int)t & 15) << 2;
    int s = src[e], d = dst[e];
    if ((unsigned)s >= N_NODES || (unsigned)d >= N_NODES) return;
    float4 v = *(const float4*)(x + (size_t)s * 64 + q);
    float* o = agg1 + (size_t)d * 64 + q;
    atomicAdd(o + 0, v.x);
    atomicAdd(o + 1, v.y);
    atomicAdd(o + 2, v.z);
    atomicAdd(o + 3, v.w);
}

// 8 threads per edge, 32-dim rows of hWl.
__global__ void k_scatter2(const int* __restrict__ src, const int* __restrict__ dst,
                           const float* __restrict__ hWl, float* __restrict__ agg2) {
    long long t = (long long)blockIdx.x * blockDim.x + threadIdx.x;
    if (t >= (long long)N_EDGES * 8) return;
    int e = (int)(t >> 3);
    int q = ((int)t & 7) << 2;
    int s = src[e], d = dst[e];
    if ((unsigned)s >= N_NODES || (unsigned)d >= N_NODES) return;
    float4 v = *(const float4*)(hWl + (size_t)s * 32 + q);
    float* o = agg2 + (size_t)d * 32 + q;
    atomicAdd(o + 0, v.x);
    atomicAdd(o + 1, v.y);
    atomicAdd(o + 2, v.z);
    atomicAdd(o + 3, v.w);
}

// Fused layer-1 GEMM + ReLU + layer-2 pre-multiplies.
// One wave per row; lane = output column.
//   h[row,l]  = relu(b1[l] + sum_k mean1[k]*W1l[l,k] + x[k]*W1r[l,k])
//   hWl[row,c] = sum_k h[k]*W2l[c,k]   (lanes 0..31)
//   hr [row,c] = sum_k h[k]*W2r[c,k]   (lanes 32..63)
// W staged in LDS k-major: s[k*L + l] -> bank = lane%32, 2 lanes/bank = conflict-free.
__global__ __launch_bounds__(256) void k_l1(
    const float* __restrict__ x, const float* __restrict__ agg1,
    const float* __restrict__ deg,
    const float* __restrict__ W1l, const float* __restrict__ W1r,
    const float* __restrict__ b1,
    const float* __restrict__ W2l, const float* __restrict__ W2r,
    float* __restrict__ hWl, float* __restrict__ hr)
{
    __shared__ float sW1l[64 * 64];
    __shared__ float sW1r[64 * 64];
    __shared__ float sW2l[64 * 32];
    __shared__ float sW2r[64 * 32];
    __shared__ float sbuf[4][3 * 64];   // per-wave: [A | X | H]

    int tid = threadIdx.x;
    // Stage weights transposed to k-major (coalesced global reads).
    for (int i = tid; i < 64 * 64; i += 256) {
        int l = i >> 6, k = i & 63;
        sW1l[k * 64 + l] = W1l[i];
        sW1r[k * 64 + l] = W1r[i];
    }
    for (int i = tid; i < 32 * 64; i += 256) {
        int c = i >> 6, k = i & 63;
        sW2l[k * 32 + c] = W2l[i];
        sW2r[k * 32 + c] = W2r[i];
    }
    __syncthreads();

    int lane = tid & 63;
    int w = tid >> 6;
    float b1v = b1[lane];
    float* bufA = sbuf[w];
    float* bufX = bufA + 64;
    float* bufH = bufA + 128;
    int c2 = lane & 31;
    const float* sW2 = (lane < 32) ? sW2l : sW2r;

    for (int base = blockIdx.x * 4; base < N_NODES; base += gridDim.x * 4) {
        int row = base + w;
        bool valid = row < N_NODES;
        if (valid) {
            float rdeg = 1.0f / fmaxf(deg[row], 1.0f);
            bufA[lane] = agg1[(size_t)row * 64 + lane] * rdeg;
            bufX[lane] = x[(size_t)row * 64 + lane];
        }
        __syncthreads();
        if (valid) {
            float acc = b1v;
            #pragma unroll
            for (int k = 0; k < 64; k += 4) {
                float4 av = *(const float4*)(bufA + k);
                float4 xv = *(const float4*)(bufX + k);
                acc = fmaf(av.x, sW1l[(k + 0) * 64 + lane], acc);
                acc = fmaf(xv.x, sW1r[(k + 0) * 64 + lane], acc);
                acc = fmaf(av.y, sW1l[(k + 1) * 64 + lane], acc);
                acc = fmaf(xv.y, sW1r[(k + 1) * 64 + lane], acc);
                acc = fmaf(av.z, sW1l[(k + 2) * 64 + lane], acc);
                acc = fmaf(xv.z, sW1r[(k + 2) * 64 + lane], acc);
                acc = fmaf(av.w, sW1l[(k + 3) * 64 + lane], acc);
                acc = fmaf(xv.w, sW1r[(k + 3) * 64 + lane], acc);
            }
            bufH[lane] = fmaxf(acc, 0.0f);
        }
        __syncthreads();
        if (valid) {
            float acc2 = 0.0f;
            #pragma unroll
            for (int k = 0; k < 64; k += 4) {
                float4 hv = *(const float4*)(bufH + k);
                acc2 = fmaf(hv.x, sW2[(k + 0) * 32 + c2], acc2);
                acc2 = fmaf(hv.y, sW2[(k + 1) * 32 + c2], acc2);
                acc2 = fmaf(hv.z, sW2[(k + 2) * 32 + c2], acc2);
                acc2 = fmaf(hv.w, sW2[(k + 3) * 32 + c2], acc2);
            }
            if (lane < 32) hWl[(size_t)row * 32 + c2] = acc2;
            else           hr [(size_t)row * 32 + c2] = acc2;
        }
        __syncthreads();
    }
}

// out[i,c] = b2[c] + agg2[i,c]/max(deg_i,1) + hr[i,c]
__global__ void k_out(const float* __restrict__ agg2, const float* __restrict__ hr,
                      const float* __restrict__ deg, const float* __restrict__ b2,
                      float* __restrict__ out) {
    int t = blockIdx.x * blockDim.x + threadIdx.x;
    if (t >= N_NODES * D_OUT) return;
    int i = t >> 5;
    int c = t & 31;
    float rdeg = 1.0f / fmaxf(deg[i], 1.0f);
    out[t] = fmaf(agg2[t], rdeg, hr[t] + b2[c]);
}

extern "C" void kernel_launch(void* const* d_in, const int* in_sizes, int n_in,
                              void* d_out, int out_size, void* d_ws, size_t ws_size,
                              hipStream_t stream) {
    const float* x   = (const float*)d_in[0];
    const int*   ei  = (const int*)d_in[1];
    const float* W1l = (const float*)d_in[2];
    const float* W1r = (const float*)d_in[3];
    const float* b1  = (const float*)d_in[4];
    const float* W2l = (const float*)d_in[5];
    const float* W2r = (const float*)d_in[6];
    const float* b2  = (const float*)d_in[7];
    float* out = (float*)d_out;
    float* ws  = (float*)d_ws;

    const int* src = ei;
    const int* dst = ei + N_EDGES;

    float* deg  = ws;
    float* agg1 = deg  + N_NODES;
    float* agg2 = agg1 + (size_t)N_NODES * 64;
    float* hWl  = agg2 + (size_t)N_NODES * 32;
    float* hr   = hWl  + (size_t)N_NODES * 32;

    // zero deg + agg1 + agg2 (contiguous 97*N floats)
    hipMemsetAsync(ws, 0, sizeof(float) * (size_t)N_NODES * 97, stream);

    k_deg<<<(N_EDGES + 255) / 256, 256, 0, stream>>>(dst, deg);
    {
        long long nt = (long long)N_EDGES * 16;
        k_scatter1<<<(int)((nt + 255) / 256), 256, 0, stream>>>(src, dst, x, agg1);
    }
    k_l1<<<768, 256, 0, stream>>>(x, agg1, deg, W1l, W1r, b1, W2l, W2r, hWl, hr);
    {
        long long nt = (long long)N_EDGES * 8;
        k_scatter2<<<(int)((nt + 255) / 256), 256, 0, stream>>>(src, dst, hWl, agg2);
    }
    k_out<<<(N_NODES * D_OUT + 255) / 256, 256, 0, stream>>>(agg2, hr, deg, b2, out);
}

// Round 2
// 832.221 us; speedup vs baseline: 2.1670x; 2.1670x over previous
//
#include <hip/hip_runtime.h>

#define N_NODES 100000
#define N_EDGES 1250000
#define D_IN 64
#define D_H 64
#define D_OUT 32

// ---------------------------------------------------------------------------
// Strategy: no value-atomics. Build CSR (counting sort by dst) each call:
//   k_hist (int atomics, 400KB counters, L2-resident)
//   k_scan (single-block exclusive scan -> row_ptr, cursor)
//   k_fill (int atomics -> csr_src[pos] = src)
// Then gather-side aggregation:
//   k_l1: per node: mean over x[src] (wave gather, lane=dim) -> layer1 GEMM
//         (+ReLU) -> premultiply by W2_l^T / W2_r^T -> hWl, hr  [32-dim each]
//         (aggregating hWl instead of h halves layer-2 gather traffic)
//   k_l2: per node: mean over hWl[src] + hr + b2 -> out
// ---------------------------------------------------------------------------

__global__ void k_hist(const int* __restrict__ dst, int* __restrict__ cnt) {
    int e = blockIdx.x * blockDim.x + threadIdx.x;
    if (e < N_EDGES) {
        int d = dst[e];
        if ((unsigned)d < N_NODES) atomicAdd(&cnt[d], 1);
    }
}

// Single-block exclusive scan of cnt[N] -> row_ptr[N+1], cursor[N] (copy).
__global__ __launch_bounds__(1024) void k_scan(const int* __restrict__ cnt,
                                               int* __restrict__ row_ptr,
                                               int* __restrict__ cursor) {
    const int T = 1024;
    const int CH = (N_NODES + T - 1) / T;   // 98
    __shared__ int part[T];
    int t = threadIdx.x;
    int lo = t * CH;
    int hi = lo + CH; if (hi > N_NODES) hi = N_NODES;
    int s = 0;
    for (int i = lo; i < hi; ++i) s += cnt[i];
    part[t] = s;
    __syncthreads();
    // Hillis-Steele inclusive scan over 1024 partials
    for (int off = 1; off < T; off <<= 1) {
        int v = (t >= off) ? part[t - off] : 0;
        __syncthreads();
        part[t] += v;
        __syncthreads();
    }
    int run = part[t] - s;   // exclusive base for this chunk
    for (int i = lo; i < hi; ++i) {
        row_ptr[i] = run;
        cursor[i] = run;
        run += cnt[i];
    }
    if (t == T - 1) row_ptr[N_NODES] = part[T - 1];
}

__global__ void k_fill(const int* __restrict__ src, const int* __restrict__ dst,
                       int* __restrict__ cursor, int* __restrict__ csr_src) {
    int e = blockIdx.x * blockDim.x + threadIdx.x;
    if (e < N_EDGES) {
        int d = dst[e];
        if ((unsigned)d >= N_NODES) return;
        int pos = atomicAdd(&cursor[d], 1);
        csr_src[pos] = src[e];
    }
}

// Fused: CSR gather-mean + layer-1 GEMM + ReLU + layer-2 premultiplies.
// One wave per node (lane = dim). 4 waves/block, grid-stride.
// LDS: 51 KB -> 3 blocks/CU (153/160 KB), 12 waves/CU.
__global__ __launch_bounds__(256) void k_l1(
    const float* __restrict__ x,
    const int* __restrict__ row_ptr, const int* __restrict__ csr_src,
    const float* __restrict__ W1l, const float* __restrict__ W1r,
    const float* __restrict__ b1,
    const float* __restrict__ W2l, const float* __restrict__ W2r,
    float* __restrict__ hWl, float* __restrict__ hr)
{
    __shared__ float sW1l[64 * 64];   // k-major: [k*64 + l]
    __shared__ float sW1r[64 * 64];
    __shared__ float sW2l[64 * 32];   // k-major: [k*32 + c]
    __shared__ float sW2r[64 * 32];
    __shared__ float sbuf[4][3 * 64]; // per-wave: [A | X | H]

    int tid = threadIdx.x;
    for (int i = tid; i < 64 * 64; i += 256) {
        int l = i >> 6, k = i & 63;
        sW1l[k * 64 + l] = W1l[i];
        sW1r[k * 64 + l] = W1r[i];
    }
    for (int i = tid; i < 32 * 64; i += 256) {
        int c = i >> 6, k = i & 63;
        sW2l[k * 32 + c] = W2l[i];
        sW2r[k * 32 + c] = W2r[i];
    }
    __syncthreads();

    int lane = tid & 63;
    int w = tid >> 6;
    float b1v = b1[lane];
    float* bufA = sbuf[w];
    float* bufX = bufA + 64;
    float* bufH = bufA + 128;
    int c2 = lane & 31;
    const float* sW2 = (lane < 32) ? sW2l : sW2r;

    for (int base = blockIdx.x * 4; base < N_NODES; base += gridDim.x * 4) {
        int row = base + w;
        bool valid = row < N_NODES;
        float acc = 0.0f;
        int deg = 0;
        if (valid) {
            int start = row_ptr[row];
            int end   = row_ptr[row + 1];
            deg = end - start;
            // Gather-sum x[src] over this node's in-edges.
            for (int eb = start; eb < end; eb += 64) {
                int nv = end - eb; if (nv > 64) nv = 64;
                int sid = (lane < nv) ? csr_src[eb + lane] : 0;
                for (int j = 0; j < nv; ++j) {
                    int s = __shfl(sid, j, 64);
                    acc += x[(size_t)s * 64 + lane];
                }
            }
            float rdeg = 1.0f / fmaxf((float)deg, 1.0f);
            bufA[lane] = acc * rdeg;
            bufX[lane] = x[(size_t)row * 64 + lane];
        }
        __syncthreads();
        if (valid) {
            float h = b1v;
            #pragma unroll
            for (int k = 0; k < 64; k += 4) {
                float4 av = *(const float4*)(bufA + k);
                float4 xv = *(const float4*)(bufX + k);
                h = fmaf(av.x, sW1l[(k + 0) * 64 + lane], h);
                h = fmaf(xv.x, sW1r[(k + 0) * 64 + lane], h);
                h = fmaf(av.y, sW1l[(k + 1) * 64 + lane], h);
                h = fmaf(xv.y, sW1r[(k + 1) * 64 + lane], h);
                h = fmaf(av.z, sW1l[(k + 2) * 64 + lane], h);
                h = fmaf(xv.z, sW1r[(k + 2) * 64 + lane], h);
                h = fmaf(av.w, sW1l[(k + 3) * 64 + lane], h);
                h = fmaf(xv.w, sW1r[(k + 3) * 64 + lane], h);
            }
            bufH[lane] = fmaxf(h, 0.0f);
        }
        __syncthreads();
        if (valid) {
            float acc2 = 0.0f;
            #pragma unroll
            for (int k = 0; k < 64; k += 4) {
                float4 hv = *(const float4*)(bufH + k);
                acc2 = fmaf(hv.x, sW2[(k + 0) * 32 + c2], acc2);
                acc2 = fmaf(hv.y, sW2[(k + 1) * 32 + c2], acc2);
                acc2 = fmaf(hv.z, sW2[(k + 2) * 32 + c2], acc2);
                acc2 = fmaf(hv.w, sW2[(k + 3) * 32 + c2], acc2);
            }
            if (lane < 32) hWl[(size_t)row * 32 + c2] = acc2;
            else           hr [(size_t)row * 32 + c2] = acc2;
        }
        __syncthreads();
    }
}

// Fused: CSR gather-mean of hWl (32-dim) + epilogue -> out.
// One wave per node: lanes 0-31 do even edges, 32-63 odd edges (c = lane&31),
// halves folded with shfl_xor(32). No LDS, no barriers.
__global__ __launch_bounds__(256) void k_l2(
    const float* __restrict__ hWl, const float* __restrict__ hr,
    const int* __restrict__ row_ptr, const int* __restrict__ csr_src,
    const float* __restrict__ b2, float* __restrict__ out)
{
    int lane = threadIdx.x & 63;
    int w = threadIdx.x >> 6;
    int c = lane & 31;
    int h = lane >> 5;           // edge parity for this half-wave
    float b2v = b2[c];

    for (int row = blockIdx.x * 4 + w; row < N_NODES; row += gridDim.x * 4) {
        int start = row_ptr[row];
        int end   = row_ptr[row + 1];
        int deg = end - start;
        float acc = 0.0f;
        for (int eb = start; eb < end; eb += 64) {
            int nv = end - eb; if (nv > 64) nv = 64;
            int sid = (lane < nv) ? csr_src[eb + lane] : 0;
            int npair = (nv + 1) >> 1;
            for (int j = 0; j < npair; ++j) {
                int idx = 2 * j + h;
                int s = __shfl(sid, idx, 64);
                if (idx < nv) acc += hWl[(size_t)s * 32 + c];
            }
        }
        acc += __shfl_xor(acc, 32, 64);   // fold odd half into even half
        if (lane < 32) {
            float rdeg = 1.0f / fmaxf((float)deg, 1.0f);
            out[(size_t)row * 32 + c] = fmaf(acc, rdeg, hr[(size_t)row * 32 + c] + b2v);
        }
    }
}

extern "C" void kernel_launch(void* const* d_in, const int* in_sizes, int n_in,
                              void* d_out, int out_size, void* d_ws, size_t ws_size,
                              hipStream_t stream) {
    const float* x   = (const float*)d_in[0];
    const int*   ei  = (const int*)d_in[1];
    const float* W1l = (const float*)d_in[2];
    const float* W1r = (const float*)d_in[3];
    const float* b1  = (const float*)d_in[4];
    const float* W2l = (const float*)d_in[5];
    const float* W2r = (const float*)d_in[6];
    const float* b2  = (const float*)d_in[7];
    float* out = (float*)d_out;

    const int* src = ei;
    const int* dst = ei + N_EDGES;

    // Workspace layout
    char* w = (char*)d_ws;
    int* cnt     = (int*)w;                       w += sizeof(int) * N_NODES;
    int* cursor  = (int*)w;                       w += sizeof(int) * N_NODES;
    int* row_ptr = (int*)w;                       w += sizeof(int) * (N_NODES + 1);
    int* csr_src = (int*)w;                       w += sizeof(int) * N_EDGES;
    float* hWl   = (float*)w;                     w += sizeof(float) * (size_t)N_NODES * 32;
    float* hr    = (float*)w;                     /* += 12.8 MB */

    hipMemsetAsync(cnt, 0, sizeof(int) * N_NODES, stream);

    k_hist<<<(N_EDGES + 255) / 256, 256, 0, stream>>>(dst, cnt);
    k_scan<<<1, 1024, 0, stream>>>(cnt, row_ptr, cursor);
    k_fill<<<(N_EDGES + 255) / 256, 256, 0, stream>>>(src, dst, cursor, csr_src);
    k_l1<<<768, 256, 0, stream>>>(x, row_ptr, csr_src, W1l, W1r, b1, W2l, W2r, hWl, hr);
    k_l2<<<1024, 256, 0, stream>>>(hWl, hr, row_ptr, csr_src, b2, out);
}

// Round 3
// 442.763 us; speedup vs baseline: 4.0731x; 1.8796x over previous
//
#include <hip/hip_runtime.h>

#define N_NODES 100000
#define N_EDGES 1250000
#define D_IN 64
#define D_H 64
#define D_OUT 32

#define SCAN_NB 98   // ceil(100000 / 1024)

// ---------------------------------------------------------------------------
// CSR build (counting sort by dst): memset cnt -> k_hist -> 3-kernel scan
// (coalesced, parallel) -> k_fill.
// Aggregation is gather-side, latency-optimized:
//   k_gather1: mean over x[src] per node -> mean1 [N*64]   (no LDS, 4-way ILP)
//   k_gemm1  : layer-1 GEMM + ReLU + premultiply by W2_l^T/W2_r^T -> hWl, hr
//   k_l2     : mean over hWl[src] + hr + b2 -> out         (no LDS, 4-way ILP)
// ---------------------------------------------------------------------------

__global__ void k_hist(const int* __restrict__ dst, int* __restrict__ cnt) {
    int e = blockIdx.x * blockDim.x + threadIdx.x;
    if (e < N_EDGES) {
        int d = dst[e];
        if ((unsigned)d < N_NODES) atomicAdd(&cnt[d], 1);
    }
}

// 98 blocks x 256 threads, 4 elements/thread: per-block sum -> part[b]
__global__ __launch_bounds__(256) void k_scan_a(const int* __restrict__ cnt,
                                                int* __restrict__ part) {
    __shared__ int red[256];
    int b = blockIdx.x, t = threadIdx.x;
    int i0 = b * 1024 + t * 4;
    int s = 0;
    if (i0 < N_NODES) {
        int4 v = *(const int4*)(cnt + i0);  // N_NODES % 4 == 0 -> full vec ok
        s = v.x + v.y + v.z + v.w;
    }
    red[t] = s;
    __syncthreads();
    for (int off = 128; off > 0; off >>= 1) {
        if (t < off) red[t] += red[t + off];
        __syncthreads();
    }
    if (t == 0) part[b] = red[0];
}

// 1 block x 128: exclusive scan of part[98] -> base[98]; writes row_ptr[N]
__global__ __launch_bounds__(128) void k_scan_b(const int* __restrict__ part,
                                                int* __restrict__ base,
                                                int* __restrict__ row_ptr) {
    __shared__ int p[128];
    int t = threadIdx.x;
    int orig = (t < SCAN_NB) ? part[t] : 0;
    p[t] = orig;
    __syncthreads();
    for (int off = 1; off < 128; off <<= 1) {
        int v = (t >= off) ? p[t - off] : 0;
        __syncthreads();
        p[t] += v;
        __syncthreads();
    }
    if (t < SCAN_NB) base[t] = p[t] - orig;
    if (t == SCAN_NB - 1) row_ptr[N_NODES] = p[t];
}

// 98 blocks x 256: block-level exclusive scan + base -> row_ptr, cursor
__global__ __launch_bounds__(256) void k_scan_c(const int* __restrict__ cnt,
                                                const int* __restrict__ base,
                                                int* __restrict__ row_ptr,
                                                int* __restrict__ cursor) {
    __shared__ int ts[256];
    int b = blockIdx.x, t = threadIdx.x;
    int i0 = b * 1024 + t * 4;
    int4 v = make_int4(0, 0, 0, 0);
    if (i0 < N_NODES) v = *(const int4*)(cnt + i0);
    int s = v.x + v.y + v.z + v.w;
    ts[t] = s;
    __syncthreads();
    for (int off = 1; off < 256; off <<= 1) {
        int u = (t >= off) ? ts[t - off] : 0;
        __syncthreads();
        ts[t] += u;
        __syncthreads();
    }
    int run = base[b] + ts[t] - s;   // exclusive prefix for this thread's 4
    if (i0 < N_NODES) {
        row_ptr[i0 + 0] = run; cursor[i0 + 0] = run; run += v.x;
        row_ptr[i0 + 1] = run; cursor[i0 + 1] = run; run += v.y;
        row_ptr[i0 + 2] = run; cursor[i0 + 2] = run; run += v.z;
        row_ptr[i0 + 3] = run; cursor[i0 + 3] = run; run += v.w;
    }
}

__global__ void k_fill(const int* __restrict__ src, const int* __restrict__ dst,
                       int* __restrict__ cursor, int* __restrict__ csr_src) {
    int e = blockIdx.x * blockDim.x + threadIdx.x;
    if (e < N_EDGES) {
        int d = dst[e];
        if ((unsigned)d >= N_NODES) return;
        int pos = atomicAdd(&cursor[d], 1);
        csr_src[pos] = src[e];
    }
}

// One wave per node, lane = dim. No LDS. 4 accumulators -> 4 outstanding
// 256B row loads per wave. Writes mean (deg-normalized).
__global__ __launch_bounds__(256) void k_gather1(
    const float* __restrict__ x,
    const int* __restrict__ row_ptr, const int* __restrict__ csr_src,
    float* __restrict__ mean1)
{
    int lane = threadIdx.x & 63;
    int w = threadIdx.x >> 6;
    for (int row = blockIdx.x * 4 + w; row < N_NODES; row += gridDim.x * 4) {
        int start = row_ptr[row];
        int end   = row_ptr[row + 1];
        int deg   = end - start;
        float a0 = 0.f, a1 = 0.f, a2 = 0.f, a3 = 0.f;
        for (int eb = start; eb < end; eb += 64) {
            int nv = end - eb; if (nv > 64) nv = 64;
            int sid = (lane < nv) ? csr_src[eb + lane] : 0;
            int j = 0;
            for (; j + 4 <= nv; j += 4) {
                int s0 = __shfl(sid, j + 0, 64);
                int s1 = __shfl(sid, j + 1, 64);
                int s2 = __shfl(sid, j + 2, 64);
                int s3 = __shfl(sid, j + 3, 64);
                a0 += x[(size_t)s0 * 64 + lane];
                a1 += x[(size_t)s1 * 64 + lane];
                a2 += x[(size_t)s2 * 64 + lane];
                a3 += x[(size_t)s3 * 64 + lane];
            }
            for (; j < nv; ++j) {
                int s = __shfl(sid, j, 64);
                a0 += x[(size_t)s * 64 + lane];
            }
        }
        float rdeg = 1.0f / fmaxf((float)deg, 1.0f);
        mean1[(size_t)row * 64 + lane] = ((a0 + a1) + (a2 + a3)) * rdeg;
    }
}

// Layer-1 GEMM + ReLU + layer-2 premultiplies. One wave per row.
// LDS weights padded (stride 65/33): staging writes AND hot reads conflict-free.
__global__ __launch_bounds__(256) void k_gemm1(
    const float* __restrict__ x, const float* __restrict__ mean1,
    const float* __restrict__ W1l, const float* __restrict__ W1r,
    const float* __restrict__ b1,
    const float* __restrict__ W2l, const float* __restrict__ W2r,
    float* __restrict__ hWl, float* __restrict__ hr)
{
    __shared__ float sW1l[64 * 65];   // [k*65 + l]
    __shared__ float sW1r[64 * 65];
    __shared__ float sW2l[64 * 33];   // [k*33 + c]
    __shared__ float sW2r[64 * 33];
    __shared__ float sbuf[4][3 * 64]; // per-wave: [A | X | H]

    int tid = threadIdx.x;
    for (int i = tid; i < 64 * 64; i += 256) {
        int l = i >> 6, k = i & 63;
        sW1l[k * 65 + l] = W1l[i];
        sW1r[k * 65 + l] = W1r[i];
    }
    for (int i = tid; i < 32 * 64; i += 256) {
        int c = i >> 6, k = i & 63;
        sW2l[k * 33 + c] = W2l[i];
        sW2r[k * 33 + c] = W2r[i];
    }
    __syncthreads();

    int lane = tid & 63;
    int w = tid >> 6;
    float b1v = b1[lane];
    float* bufA = sbuf[w];
    float* bufX = bufA + 64;
    float* bufH = bufA + 128;
    int c2 = lane & 31;
    const float* sW2 = (lane < 32) ? sW2l : sW2r;

    for (int base = blockIdx.x * 4; base < N_NODES; base += gridDim.x * 4) {
        int row = base + w;
        bool valid = row < N_NODES;
        if (valid) {
            bufA[lane] = mean1[(size_t)row * 64 + lane];
            bufX[lane] = x[(size_t)row * 64 + lane];
        }
        __syncthreads();
        if (valid) {
            float h = b1v;
            #pragma unroll
            for (int k = 0; k < 64; k += 4) {
                float4 av = *(const float4*)(bufA + k);
                float4 xv = *(const float4*)(bufX + k);
                h = fmaf(av.x, sW1l[(k + 0) * 65 + lane], h);
                h = fmaf(xv.x, sW1r[(k + 0) * 65 + lane], h);
                h = fmaf(av.y, sW1l[(k + 1) * 65 + lane], h);
                h = fmaf(xv.y, sW1r[(k + 1) * 65 + lane], h);
                h = fmaf(av.z, sW1l[(k + 2) * 65 + lane], h);
                h = fmaf(xv.z, sW1r[(k + 2) * 65 + lane], h);
                h = fmaf(av.w, sW1l[(k + 3) * 65 + lane], h);
                h = fmaf(xv.w, sW1r[(k + 3) * 65 + lane], h);
            }
            bufH[lane] = fmaxf(h, 0.0f);
        }
        __syncthreads();
        if (valid) {
            float acc2 = 0.0f;
            #pragma unroll
            for (int k = 0; k < 64; k += 4) {
                float4 hv = *(const float4*)(bufH + k);
                acc2 = fmaf(hv.x, sW2[(k + 0) * 33 + c2], acc2);
                acc2 = fmaf(hv.y, sW2[(k + 1) * 33 + c2], acc2);
                acc2 = fmaf(hv.z, sW2[(k + 2) * 33 + c2], acc2);
                acc2 = fmaf(hv.w, sW2[(k + 3) * 33 + c2], acc2);
            }
            if (lane < 32) hWl[(size_t)row * 32 + c2] = acc2;
            else           hr [(size_t)row * 32 + c2] = acc2;
        }
        __syncthreads();
    }
}

// Gather-mean of hWl (32-dim) + epilogue. Half-waves take even/odd edges
// (c = lane&31), 4 accumulators each -> 8 rows in flight per wave.
__global__ __launch_bounds__(256) void k_l2(
    const float* __restrict__ hWl, const float* __restrict__ hr,
    const int* __restrict__ row_ptr, const int* __restrict__ csr_src,
    const float* __restrict__ b2, float* __restrict__ out)
{
    int lane = threadIdx.x & 63;
    int w = threadIdx.x >> 6;
    int c = lane & 31;
    int h = lane >> 5;           // edge parity for this half-wave
    float b2v = b2[c];

    for (int row = blockIdx.x * 4 + w; row < N_NODES; row += gridDim.x * 4) {
        int start = row_ptr[row];
        int end   = row_ptr[row + 1];
        int deg = end - start;
        float a0 = 0.f, a1 = 0.f, a2 = 0.f, a3 = 0.f;
        for (int eb = start; eb < end; eb += 64) {
            int nv = end - eb; if (nv > 64) nv = 64;
            int sid = (lane < nv) ? csr_src[eb + lane] : 0;
            int j = 0;
            for (; j + 8 <= nv; j += 8) {
                int s0 = __shfl(sid, j + 0 + h, 64);
                int s1 = __shfl(sid, j + 2 + h, 64);
                int s2 = __shfl(sid, j + 4 + h, 64);
                int s3 = __shfl(sid, j + 6 + h, 64);
                a0 += hWl[(size_t)s0 * 32 + c];
                a1 += hWl[(size_t)s1 * 32 + c];
                a2 += hWl[(size_t)s2 * 32 + c];
                a3 += hWl[(size_t)s3 * 32 + c];
            }
            for (; j < nv; j += 4) {
                int i0 = j + 0 + h, i1 = j + 2 + h;
                int s0 = __shfl(sid, (i0 < 64) ? i0 : 0, 64);
                int s1 = __shfl(sid, (i1 < 64) ? i1 : 0, 64);
                if (i0 < nv) a0 += hWl[(size_t)s0 * 32 + c];
                if (i1 < nv) a1 += hWl[(size_t)s1 * 32 + c];
            }
        }
        float acc = (a0 + a1) + (a2 + a3);
        acc += __shfl_xor(acc, 32, 64);   // fold odd half into even half
        if (lane < 32) {
            float rdeg = 1.0f / fmaxf((float)deg, 1.0f);
            out[(size_t)row * 32 + c] = fmaf(acc, rdeg, hr[(size_t)row * 32 + c] + b2v);
        }
    }
}

extern "C" void kernel_launch(void* const* d_in, const int* in_sizes, int n_in,
                              void* d_out, int out_size, void* d_ws, size_t ws_size,
                              hipStream_t stream) {
    const float* x   = (const float*)d_in[0];
    const int*   ei  = (const int*)d_in[1];
    const float* W1l = (const float*)d_in[2];
    const float* W1r = (const float*)d_in[3];
    const float* b1  = (const float*)d_in[4];
    const float* W2l = (const float*)d_in[5];
    const float* W2r = (const float*)d_in[6];
    const float* b2  = (const float*)d_in[7];
    float* out = (float*)d_out;

    const int* src = ei;
    const int* dst = ei + N_EDGES;

    // Workspace layout
    char* w = (char*)d_ws;
    int* cnt     = (int*)w;   w += sizeof(int) * N_NODES;
    int* cursor  = (int*)w;   w += sizeof(int) * N_NODES;
    int* row_ptr = (int*)w;   w += sizeof(int) * (N_NODES + 4);
    int* part    = (int*)w;   w += sizeof(int) * 128;
    int* base    = (int*)w;   w += sizeof(int) * 128;
    int* csr_src = (int*)w;   w += sizeof(int) * N_EDGES;
    float* mean1 = (float*)w; w += sizeof(float) * (size_t)N_NODES * 64;
    float* hWl   = (float*)w; w += sizeof(float) * (size_t)N_NODES * 32;
    float* hr    = (float*)w; /* += 12.8 MB ; total ~58 MB */

    hipMemsetAsync(cnt, 0, sizeof(int) * N_NODES, stream);

    k_hist<<<(N_EDGES + 255) / 256, 256, 0, stream>>>(dst, cnt);
    k_scan_a<<<SCAN_NB, 256, 0, stream>>>(cnt, part);
    k_scan_b<<<1, 128, 0, stream>>>(part, base, row_ptr);
    k_scan_c<<<SCAN_NB, 256, 0, stream>>>(cnt, base, row_ptr, cursor);
    k_fill<<<(N_EDGES + 255) / 256, 256, 0, stream>>>(src, dst, cursor, csr_src);
    k_gather1<<<2048, 256, 0, stream>>>(x, row_ptr, csr_src, mean1);
    k_gemm1<<<768, 256, 0, stream>>>(x, mean1, W1l, W1r, b1, W2l, W2r, hWl, hr);
    k_l2<<<2048, 256, 0, stream>>>(hWl, hr, row_ptr, csr_src, b2, out);
}

// Round 4
// 346.851 us; speedup vs baseline: 5.1994x; 1.2765x over previous
//
#include <hip/hip_runtime.h>

#define N_NODES 100000
#define N_EDGES 1250000
#define D_IN 64
#define D_H 64
#define D_OUT 32

#define SCAN_NB 98   // ceil(100000 / 1024)

typedef __attribute__((ext_vector_type(8))) short bf16x8;
typedef __attribute__((ext_vector_type(4))) float f32x4;

__device__ __forceinline__ unsigned short f2bf(float f) {
    unsigned u = __float_as_uint(f);
    u = (u + 0x7fffu + ((u >> 16) & 1u)) >> 16;   // RNE
    return (unsigned short)u;
}
__device__ __forceinline__ float bfhi(unsigned v) { return __uint_as_float(v & 0xffff0000u); }
__device__ __forceinline__ float bflo(unsigned v) { return __uint_as_float(v << 16); }

// ---------------------------------------------------------------------------
// Pipeline: tobf16(x->xh) ; CSR build (hist -> scan -> fill) ;
//   k_gather1: mean over xh[src] (bf16 rows, 2 edges/wave, 4-way ILP) -> meanh
//   k_gemm1  : MFMA bf16: h=relu([mean|x]@[W1l|W1r]^T+b1); hWl=h@W2l^T (bf16),
//              hr=h@W2r^T (fp32)
//   k_l2     : mean over hWl[src] (bf16, 4 edges/wave) + hr + b2 -> out
// ---------------------------------------------------------------------------

__global__ void k_tobf16(const float* __restrict__ x, unsigned short* __restrict__ xh) {
    int t = blockIdx.x * blockDim.x + threadIdx.x;
    int i = t * 4;
    if (i < N_NODES * 64) {
        float4 v = *(const float4*)(x + i);
        uint2 u;
        u.x = (unsigned)f2bf(v.x) | ((unsigned)f2bf(v.y) << 16);
        u.y = (unsigned)f2bf(v.z) | ((unsigned)f2bf(v.w) << 16);
        *(uint2*)(xh + i) = u;
    }
}

__global__ void k_hist(const int* __restrict__ dst, int* __restrict__ cnt) {
    int e = blockIdx.x * blockDim.x + threadIdx.x;
    if (e < N_EDGES) {
        int d = dst[e];
        if ((unsigned)d < N_NODES) atomicAdd(&cnt[d], 1);
    }
}

__global__ __launch_bounds__(256) void k_scan_a(const int* __restrict__ cnt,
                                                int* __restrict__ part) {
    __shared__ int red[256];
    int b = blockIdx.x, t = threadIdx.x;
    int i0 = b * 1024 + t * 4;
    int s = 0;
    if (i0 < N_NODES) {
        int4 v = *(const int4*)(cnt + i0);
        s = v.x + v.y + v.z + v.w;
    }
    red[t] = s;
    __syncthreads();
    for (int off = 128; off > 0; off >>= 1) {
        if (t < off) red[t] += red[t + off];
        __syncthreads();
    }
    if (t == 0) part[b] = red[0];
}

__global__ __launch_bounds__(128) void k_scan_b(const int* __restrict__ part,
                                                int* __restrict__ base,
                                                int* __restrict__ row_ptr) {
    __shared__ int p[128];
    int t = threadIdx.x;
    int orig = (t < SCAN_NB) ? part[t] : 0;
    p[t] = orig;
    __syncthreads();
    for (int off = 1; off < 128; off <<= 1) {
        int v = (t >= off) ? p[t - off] : 0;
        __syncthreads();
        p[t] += v;
        __syncthreads();
    }
    if (t < SCAN_NB) base[t] = p[t] - orig;
    if (t == SCAN_NB - 1) row_ptr[N_NODES] = p[t];
}

__global__ __launch_bounds__(256) void k_scan_c(const int* __restrict__ cnt,
                                                const int* __restrict__ base,
                                                int* __restrict__ row_ptr,
                                                int* __restrict__ cursor) {
    __shared__ int ts[256];
    int b = blockIdx.x, t = threadIdx.x;
    int i0 = b * 1024 + t * 4;
    int4 v = make_int4(0, 0, 0, 0);
    if (i0 < N_NODES) v = *(const int4*)(cnt + i0);
    int s = v.x + v.y + v.z + v.w;
    ts[t] = s;
    __syncthreads();
    for (int off = 1; off < 256; off <<= 1) {
        int u = (t >= off) ? ts[t - off] : 0;
        __syncthreads();
        ts[t] += u;
        __syncthreads();
    }
    int run = base[b] + ts[t] - s;
    if (i0 < N_NODES) {
        row_ptr[i0 + 0] = run; cursor[i0 + 0] = run; run += v.x;
        row_ptr[i0 + 1] = run; cursor[i0 + 1] = run; run += v.y;
        row_ptr[i0 + 2] = run; cursor[i0 + 2] = run; run += v.z;
        row_ptr[i0 + 3] = run; cursor[i0 + 3] = run; run += v.w;
    }
}

__global__ void k_fill(const int* __restrict__ src, const int* __restrict__ dst,
                       int* __restrict__ cursor, int* __restrict__ csr_src) {
    int e = blockIdx.x * blockDim.x + threadIdx.x;
    if (e < N_EDGES) {
        int d = dst[e];
        if ((unsigned)d >= N_NODES) return;
        int pos = atomicAdd(&cursor[d], 1);
        csr_src[pos] = src[e];
    }
}

// One wave per node. lane = 32*p + c: half-wave p handles edge parity p,
// lane covers dims (2c, 2c+1) as one bfloat162 (4B) load. 4-deep unroll
// -> 8 row-loads in flight per wave. Output meanh bf16.
__global__ __launch_bounds__(256) void k_gather1(
    const unsigned short* __restrict__ xh,
    const int* __restrict__ row_ptr, const int* __restrict__ csr_src,
    unsigned int* __restrict__ meanh)
{
    int lane = threadIdx.x & 63;
    int w = threadIdx.x >> 6;
    int c = lane & 31;
    int p = lane >> 5;
    const unsigned int* xp = (const unsigned int*)xh;   // row = 32 uints

    for (int row = blockIdx.x * 4 + w; row < N_NODES; row += gridDim.x * 4) {
        int start = row_ptr[row];
        int end   = row_ptr[row + 1];
        int deg   = end - start;
        float x0 = 0.f, y0 = 0.f, x1 = 0.f, y1 = 0.f;
        float x2 = 0.f, y2 = 0.f, x3 = 0.f, y3 = 0.f;
        for (int eb = start; eb < end; eb += 64) {
            int nv = end - eb; if (nv > 64) nv = 64;
            int sid = (lane < nv) ? csr_src[eb + lane] : 0;
            if (nv == 64) {
                for (int j = 0; j < 64; j += 8) {
                    int s0 = __shfl(sid, j + 0 + p, 64);
                    int s1 = __shfl(sid, j + 2 + p, 64);
                    int s2 = __shfl(sid, j + 4 + p, 64);
                    int s3 = __shfl(sid, j + 6 + p, 64);
                    unsigned v0 = xp[s0 * 32 + c];
                    unsigned v1 = xp[s1 * 32 + c];
                    unsigned v2 = xp[s2 * 32 + c];
                    unsigned v3 = xp[s3 * 32 + c];
                    x0 += bflo(v0); y0 += bfhi(v0);
                    x1 += bflo(v1); y1 += bfhi(v1);
                    x2 += bflo(v2); y2 += bfhi(v2);
                    x3 += bflo(v3); y3 += bfhi(v3);
                }
            } else {
                for (int j = 0; j < nv; j += 2) {
                    int i = j + p;
                    int s = __shfl(sid, (i < 64) ? i : 0, 64);
                    if (i < nv) {
                        unsigned v = xp[s * 32 + c];
                        x0 += bflo(v); y0 += bfhi(v);
                    }
                }
            }
        }
        float fx = (x0 + x1) + (x2 + x3);
        float fy = (y0 + y1) + (y2 + y3);
        fx += __shfl_xor(fx, 32, 64);
        fy += __shfl_xor(fy, 32, 64);
        if (lane < 32) {
            float rdeg = 1.0f / fmaxf((float)deg, 1.0f);
            meanh[row * 32 + c] =
                (unsigned)f2bf(fx * rdeg) | ((unsigned)f2bf(fy * rdeg) << 16);
        }
    }
}

// MFMA bf16: wave computes 16 rows.
//  L1: [mean|x](16x128) @ W1cat^T -> h (+b1, relu)        16 MFMA 16x16x32
//  L2: h(16x64, via LDS relayout) @ W2cat^T -> hWl | hr    8 MFMA
// B-fragments pre-swizzled in LDS (1 ds_read_b128 per MFMA, conflict-free).
// A frag: lane holds A[m=lane&15][k = kc*32 + (lane>>4)*8 + j], j=0..7.
// C/D:    lane holds D[row=(lane>>4)*4+reg][col=lane&15] (verified m89).
__global__ __launch_bounds__(256) void k_gemm1(
    const unsigned short* __restrict__ xh, const unsigned short* __restrict__ meanh,
    const float* __restrict__ W1l, const float* __restrict__ W1r,
    const float* __restrict__ b1,
    const float* __restrict__ W2l, const float* __restrict__ W2r,
    unsigned short* __restrict__ hWlh, float* __restrict__ hr)
{
    __shared__ short sWB1[4 * 4 * 64 * 8];   // [kc][nt][lane][8]  16 KB
    __shared__ short sWB2[2 * 4 * 64 * 8];   // [kc2][nt][lane][8]  8 KB
    __shared__ short htile[4][16 * 72];      // per-wave h tile, stride 72 (16B-aligned)

    int tid = threadIdx.x;
    // Stage B1 fragments: W1cat[n][k] = k<64 ? W1l[n][k] : W1r[n][k-64]
    for (int e = tid; e < 1024; e += 256) {
        int kc = e >> 8, nt = (e >> 6) & 3, ln = e & 63;
        int cc = ln & 15, qd = ln >> 4;
        int n = nt * 16 + cc, k0 = kc * 32 + qd * 8;
        const float* sp = (k0 < 64) ? (W1l + n * 64 + k0) : (W1r + n * 64 + (k0 - 64));
        short* dp = sWB1 + e * 8;
        #pragma unroll
        for (int j = 0; j < 8; ++j) dp[j] = (short)f2bf(sp[j]);
    }
    // Stage B2 fragments: W2cat[n][k] = n<32 ? W2l[n][k] : W2r[n-32][k]
    for (int e = tid; e < 512; e += 256) {
        int kc = e >> 8, nt = (e >> 6) & 3, ln = e & 63;
        int cc = ln & 15, qd = ln >> 4;
        int n = nt * 16 + cc, k0 = kc * 32 + qd * 8;
        const float* sp = (n < 32) ? (W2l + n * 64 + k0) : (W2r + (n - 32) * 64 + k0);
        short* dp = sWB2 + e * 8;
        #pragma unroll
        for (int j = 0; j < 8; ++j) dp[j] = (short)f2bf(sp[j]);
    }
    __syncthreads();

    int lane = tid & 63, w = tid >> 6;
    int c = lane & 15, quad = lane >> 4;
    float bias[4];
    #pragma unroll
    for (int nt = 0; nt < 4; ++nt) bias[nt] = b1[nt * 16 + c];

    const bf16x8* B1 = (const bf16x8*)sWB1;
    const bf16x8* B2 = (const bf16x8*)sWB2;
    short* ht = htile[w];

    for (int r0 = blockIdx.x * 64 + w * 16; r0 < N_NODES; r0 += gridDim.x * 64) {
        int ra = r0 + c; if (ra > N_NODES - 1) ra = N_NODES - 1;
        const bf16x8* mrow = (const bf16x8*)(meanh + (size_t)ra * 32 * 2 / 2 * 0 + 0); // placeholder
        // meanh is uint*; reinterpret as shorts: row = 64 shorts
        mrow = (const bf16x8*)((const unsigned short*)meanh + (size_t)ra * 64);
        const bf16x8* xrow = (const bf16x8*)(xh + (size_t)ra * 64);
        bf16x8 a0 = mrow[quad];       // kc=0: k in [0,32)
        bf16x8 a1 = mrow[4 + quad];   // kc=1: k in [32,64)
        bf16x8 a2 = xrow[quad];       // kc=2
        bf16x8 a3 = xrow[4 + quad];   // kc=3

        f32x4 acc[4];
        #pragma unroll
        for (int nt = 0; nt < 4; ++nt) acc[nt] = (f32x4){0.f, 0.f, 0.f, 0.f};
        #pragma unroll
        for (int nt = 0; nt < 4; ++nt)
            acc[nt] = __builtin_amdgcn_mfma_f32_16x16x32_bf16(a0, B1[(0 * 4 + nt) * 64 + lane], acc[nt], 0, 0, 0);
        #pragma unroll
        for (int nt = 0; nt < 4; ++nt)
            acc[nt] = __builtin_amdgcn_mfma_f32_16x16x32_bf16(a1, B1[(1 * 4 + nt) * 64 + lane], acc[nt], 0, 0, 0);
        #pragma unroll
        for (int nt = 0; nt < 4; ++nt)
            acc[nt] = __builtin_amdgcn_mfma_f32_16x16x32_bf16(a2, B1[(2 * 4 + nt) * 64 + lane], acc[nt], 0, 0, 0);
        #pragma unroll
        for (int nt = 0; nt < 4; ++nt)
            acc[nt] = __builtin_amdgcn_mfma_f32_16x16x32_bf16(a3, B1[(3 * 4 + nt) * 64 + lane], acc[nt], 0, 0, 0);

        // h = relu(acc+bias) -> bf16 -> LDS tile (row-major, stride 72)
        #pragma unroll
        for (int nt = 0; nt < 4; ++nt) {
            #pragma unroll
            for (int reg = 0; reg < 4; ++reg) {
                float hv = fmaxf(acc[nt][reg] + bias[nt], 0.0f);
                ht[(quad * 4 + reg) * 72 + nt * 16 + c] = (short)f2bf(hv);
            }
        }
        // A2 frags: contiguous 8 shorts, 16B-aligned (72*2=144=16*9)
        bf16x8 h0 = *(const bf16x8*)(ht + c * 72 + 0  + quad * 8);
        bf16x8 h1 = *(const bf16x8*)(ht + c * 72 + 32 + quad * 8);

        f32x4 acc2[4];
        #pragma unroll
        for (int nt = 0; nt < 4; ++nt) acc2[nt] = (f32x4){0.f, 0.f, 0.f, 0.f};
        #pragma unroll
        for (int nt = 0; nt < 4; ++nt)
            acc2[nt] = __builtin_amdgcn_mfma_f32_16x16x32_bf16(h0, B2[(0 * 4 + nt) * 64 + lane], acc2[nt], 0, 0, 0);
        #pragma unroll
        for (int nt = 0; nt < 4; ++nt)
            acc2[nt] = __builtin_amdgcn_mfma_f32_16x16x32_bf16(h1, B2[(1 * 4 + nt) * 64 + lane], acc2[nt], 0, 0, 0);

        // cols 0-31 -> hWl (bf16), cols 32-63 -> hr (fp32)
        #pragma unroll
        for (int nt = 0; nt < 4; ++nt) {
            #pragma unroll
            for (int reg = 0; reg < 4; ++reg) {
                int row = r0 + quad * 4 + reg;
                if (row < N_NODES) {
                    if (nt < 2) hWlh[(size_t)row * 32 + nt * 16 + c] = f2bf(acc2[nt][reg]);
                    else        hr[(size_t)row * 32 + (nt - 2) * 16 + c] = acc2[nt][reg];
                }
            }
        }
    }
}

// One wave per node. lane = 16*q + c: quarter q handles edges =q mod 4,
// lane covers dims (2c,2c+1) of bf16 hWl row (64B). 4-deep unroll ->
// 16 row-loads in flight per wave. Epilogue: +hr +b2 -> out.
__global__ __launch_bounds__(256) void k_l2(
    const unsigned short* __restrict__ hWlh, const float* __restrict__ hr,
    const int* __restrict__ row_ptr, const int* __restrict__ csr_src,
    const float* __restrict__ b2, float* __restrict__ out)
{
    int lane = threadIdx.x & 63;
    int w = threadIdx.x >> 6;
    int c = lane & 15;
    int q = lane >> 4;
    const unsigned int* hp = (const unsigned int*)hWlh;   // row = 16 uints
    float2 b2v = ((const float2*)b2)[c];

    for (int row = blockIdx.x * 4 + w; row < N_NODES; row += gridDim.x * 4) {
        int start = row_ptr[row];
        int end   = row_ptr[row + 1];
        int deg = end - start;
        float x0 = 0.f, y0 = 0.f, x1 = 0.f, y1 = 0.f;
        float x2 = 0.f, y2 = 0.f, x3 = 0.f, y3 = 0.f;
        for (int eb = start; eb < end; eb += 64) {
            int nv = end - eb; if (nv > 64) nv = 64;
            int sid = (lane < nv) ? csr_src[eb + lane] : 0;
            if (nv == 64) {
                for (int j = 0; j < 64; j += 16) {
                    int s0 = __shfl(sid, j + 0  + q, 64);
                    int s1 = __shfl(sid, j + 4  + q, 64);
                    int s2 = __shfl(sid, j + 8  + q, 64);
                    int s3 = __shfl(sid, j + 12 + q, 64);
                    unsigned v0 = hp[s0 * 16 + c];
                    unsigned v1 = hp[s1 * 16 + c];
                    unsigned v2 = hp[s2 * 16 + c];
                    unsigned v3 = hp[s3 * 16 + c];
                    x0 += bflo(v0); y0 += bfhi(v0);
                    x1 += bflo(v1); y1 += bfhi(v1);
                    x2 += bflo(v2); y2 += bfhi(v2);
                    x3 += bflo(v3); y3 += bfhi(v3);
                }
            } else {
                for (int j = 0; j < nv; j += 4) {
                    int i = j + q;
                    int s = __shfl(sid, (i < 64) ? i : 0, 64);
                    if (i < nv) {
                        unsigned v = hp[s * 16 + c];
                        x0 += bflo(v); y0 += bfhi(v);
                    }
                }
            }
        }
        float fx = (x0 + x1) + (x2 + x3);
        float fy = (y0 + y1) + (y2 + y3);
        fx += __shfl_xor(fx, 16, 64);
        fy += __shfl_xor(fy, 16, 64);
        fx += __shfl_xor(fx, 32, 64);
        fy += __shfl_xor(fy, 32, 64);
        if (lane < 16) {
            float rdeg = 1.0f / fmaxf((float)deg, 1.0f);
            float2 hv = ((const float2*)hr)[(size_t)row * 16 + c];
            float2 o;
            o.x = fmaf(fx, rdeg, hv.x + b2v.x);
            o.y = fmaf(fy, rdeg, hv.y + b2v.y);
            ((float2*)out)[(size_t)row * 16 + c] = o;
        }
    }
}

extern "C" void kernel_launch(void* const* d_in, const int* in_sizes, int n_in,
                              void* d_out, int out_size, void* d_ws, size_t ws_size,
                              hipStream_t stream) {
    const float* x   = (const float*)d_in[0];
    const int*   ei  = (const int*)d_in[1];
    const float* W1l = (const float*)d_in[2];
    const float* W1r = (const float*)d_in[3];
    const float* b1  = (const float*)d_in[4];
    const float* W2l = (const float*)d_in[5];
    const float* W2r = (const float*)d_in[6];
    const float* b2  = (const float*)d_in[7];
    float* out = (float*)d_out;

    const int* src = ei;
    const int* dst = ei + N_EDGES;

    char* w = (char*)d_ws;
    int* cnt     = (int*)w;   w += sizeof(int) * N_NODES;
    int* cursor  = (int*)w;   w += sizeof(int) * N_NODES;
    int* row_ptr = (int*)w;   w += sizeof(int) * (N_NODES + 4);
    int* part    = (int*)w;   w += sizeof(int) * 128;
    int* base    = (int*)w;   w += sizeof(int) * 128;
    int* csr_src = (int*)w;   w += sizeof(int) * N_EDGES;
    unsigned short* xh    = (unsigned short*)w; w += sizeof(short) * (size_t)N_NODES * 64;
    unsigned int*   meanh = (unsigned int*)w;   w += sizeof(int)   * (size_t)N_NODES * 32;
    unsigned short* hWlh  = (unsigned short*)w; w += sizeof(short) * (size_t)N_NODES * 32;
    float*          hr    = (float*)w;          /* + 12.8 MB; total ~51 MB */

    hipMemsetAsync(cnt, 0, sizeof(int) * N_NODES, stream);

    k_tobf16<<<(N_NODES * 64 / 4 + 255) / 256, 256, 0, stream>>>(x, xh);
    k_hist<<<(N_EDGES + 255) / 256, 256, 0, stream>>>(dst, cnt);
    k_scan_a<<<SCAN_NB, 256, 0, stream>>>(cnt, part);
    k_scan_b<<<1, 128, 0, stream>>>(part, base, row_ptr);
    k_scan_c<<<SCAN_NB, 256, 0, stream>>>(cnt, base, row_ptr, cursor);
    k_fill<<<(N_EDGES + 255) / 256, 256, 0, stream>>>(src, dst, cursor, csr_src);
    k_gather1<<<2048, 256, 0, stream>>>(xh, row_ptr, csr_src, meanh);
    k_gemm1<<<(N_NODES + 63) / 64, 256, 0, stream>>>(
        xh, (const unsigned short*)meanh, W1l, W1r, b1, W2l, W2r, hWlh, hr);
    k_l2<<<2048, 256, 0, stream>>>(hWlh, hr, row_ptr, csr_src, b2, out);
}

// Round 5
// 290.591 us; speedup vs baseline: 6.2061x; 1.1936x over previous
//
#include <hip/hip_runtime.h>

#define N_NODES 100000
#define N_EDGES 1250000
#define D_IN 64
#define D_H 64
#define D_OUT 32

#define SCAN_NB 98     // ceil(100000 / 1024)
#define BUCKETS 196    // ceil(100000 / 512)
#define GRP 512        // nodes per bucket (dst >> 9)
#define PHA_CHUNK 8192
#define PHA_NB 153     // ceil(1250000 / 8192)

typedef __attribute__((ext_vector_type(8))) short bf16x8;
typedef __attribute__((ext_vector_type(4))) float f32x4;

__device__ __forceinline__ unsigned short f2bf(float f) {
    unsigned u = __float_as_uint(f);
    u = (u + 0x7fffu + ((u >> 16) & 1u)) >> 16;   // RNE
    return (unsigned short)u;
}
__device__ __forceinline__ float bfhi(unsigned v) { return __uint_as_float(v & 0xffff0000u); }
__device__ __forceinline__ float bflo(unsigned v) { return __uint_as_float(v << 16); }

// ---------------------------------------------------------------------------
// Pipeline: tobf16(x->xh) ; hist -> scan (row_ptr + bucket bases) ;
//   k_pha: bucket edges by dst>>9 into ebuf (contiguous per-block runs)
//   k_phb: per-bucket counting sort (LDS cursors) -> csr_src (block-local writes)
//   k_gather1: mean over xh[src] (bf16, 2 edges/wave, 4-way ILP) -> meanh
//   k_gemm1  : MFMA bf16: h=relu([mean|x]@[W1l|W1r]^T+b1); hWl=h@W2l^T (bf16),
//              hr=h@W2r^T (fp32)
//   k_l2     : mean over hWl[src] (bf16, 4 edges/wave) + hr + b2 -> out
// ---------------------------------------------------------------------------

__global__ void k_tobf16(const float* __restrict__ x, unsigned short* __restrict__ xh) {
    int t = blockIdx.x * blockDim.x + threadIdx.x;
    int i = t * 4;
    if (i < N_NODES * 64) {
        float4 v = *(const float4*)(x + i);
        uint2 u;
        u.x = (unsigned)f2bf(v.x) | ((unsigned)f2bf(v.y) << 16);
        u.y = (unsigned)f2bf(v.z) | ((unsigned)f2bf(v.w) << 16);
        *(uint2*)(xh + i) = u;
    }
}

__global__ void k_hist(const int* __restrict__ dst, int* __restrict__ cnt) {
    int e = blockIdx.x * blockDim.x + threadIdx.x;
    if (e < N_EDGES) {
        int d = dst[e];
        if ((unsigned)d < N_NODES) atomicAdd(&cnt[d], 1);
    }
}

__global__ __launch_bounds__(256) void k_scan_a(const int* __restrict__ cnt,
                                                int* __restrict__ part) {
    __shared__ int red[256];
    int b = blockIdx.x, t = threadIdx.x;
    int i0 = b * 1024 + t * 4;
    int s = 0;
    if (i0 < N_NODES) {
        int4 v = *(const int4*)(cnt + i0);
        s = v.x + v.y + v.z + v.w;
    }
    red[t] = s;
    __syncthreads();
    for (int off = 128; off > 0; off >>= 1) {
        if (t < off) red[t] += red[t + off];
        __syncthreads();
    }
    if (t == 0) part[b] = red[0];
}

__global__ __launch_bounds__(128) void k_scan_b(const int* __restrict__ part,
                                                int* __restrict__ base,
                                                int* __restrict__ row_ptr) {
    __shared__ int p[128];
    int t = threadIdx.x;
    int orig = (t < SCAN_NB) ? part[t] : 0;
    p[t] = orig;
    __syncthreads();
    for (int off = 1; off < 128; off <<= 1) {
        int v = (t >= off) ? p[t - off] : 0;
        __syncthreads();
        p[t] += v;
        __syncthreads();
    }
    if (t < SCAN_NB) base[t] = p[t] - orig;
    if (t == SCAN_NB - 1) row_ptr[N_NODES] = p[t];
}

// row_ptr + bucket cursors (bcur[b] = row_ptr[b*GRP], consumed by k_pha)
__global__ __launch_bounds__(256) void k_scan_c(const int* __restrict__ cnt,
                                                const int* __restrict__ base,
                                                int* __restrict__ row_ptr,
                                                int* __restrict__ bcur) {
    __shared__ int ts[256];
    int b = blockIdx.x, t = threadIdx.x;
    int i0 = b * 1024 + t * 4;
    int4 v = make_int4(0, 0, 0, 0);
    if (i0 < N_NODES) v = *(const int4*)(cnt + i0);
    int s = v.x + v.y + v.z + v.w;
    ts[t] = s;
    __syncthreads();
    for (int off = 1; off < 256; off <<= 1) {
        int u = (t >= off) ? ts[t - off] : 0;
        __syncthreads();
        ts[t] += u;
        __syncthreads();
    }
    int run = base[b] + ts[t] - s;
    if (i0 < N_NODES) {
        if ((i0 & (GRP - 1)) == 0) bcur[i0 >> 9] = run;
        row_ptr[i0 + 0] = run; run += v.x;
        row_ptr[i0 + 1] = run; run += v.y;
        row_ptr[i0 + 2] = run; run += v.z;
        row_ptr[i0 + 3] = run; run += v.w;
    }
}

// Phase A: bucket edges by dst>>9. Per-block LDS histogram -> one global
// atomic per bucket -> contiguous per-block runs of (src,dst) pairs in ebuf.
__global__ __launch_bounds__(256) void k_pha(const int* __restrict__ src,
                                             const int* __restrict__ dst,
                                             int* __restrict__ bcur,
                                             int2* __restrict__ ebuf) {
    __shared__ int hist[BUCKETS];
    __shared__ int bbase[BUCKETS];
    __shared__ int ofs[BUCKETS];
    int t = threadIdx.x;
    for (int i = t; i < BUCKETS; i += 256) { hist[i] = 0; ofs[i] = 0; }
    __syncthreads();
    int e0 = blockIdx.x * PHA_CHUNK;
    int e1 = e0 + PHA_CHUNK; if (e1 > N_EDGES) e1 = N_EDGES;
    for (int e = e0 + t; e < e1; e += 256)
        atomicAdd(&hist[dst[e] >> 9], 1);
    __syncthreads();
    for (int i = t; i < BUCKETS; i += 256) {
        int h = hist[i];
        bbase[i] = h ? atomicAdd(&bcur[i], h) : 0;
    }
    __syncthreads();
    for (int e = e0 + t; e < e1; e += 256) {
        int s = src[e], d = dst[e];
        int b = d >> 9;
        int r = atomicAdd(&ofs[b], 1);
        ebuf[bbase[b] + r] = make_int2(s, d);
    }
}

// Phase B: one block per bucket. LDS cursors (init from row_ptr) -> all
// position atomics in LDS; csr writes stay within this block's ~25KB span.
__global__ __launch_bounds__(256) void k_phb(const int2* __restrict__ ebuf,
                                             const int* __restrict__ row_ptr,
                                             int* __restrict__ csr_src) {
    __shared__ int cur[GRP];
    int b = blockIdx.x, t = threadIdx.x;
    int lo = b * GRP;
    int hi = lo + GRP; if (hi > N_NODES) hi = N_NODES;
    int n = hi - lo;
    for (int i = t; i < n; i += 256) cur[i] = row_ptr[lo + i];
    __syncthreads();
    int start = row_ptr[lo], end = row_ptr[hi];
    for (int e = start + t; e < end; e += 256) {
        int2 p = ebuf[e];
        int pos = atomicAdd(&cur[p.y - lo], 1);
        csr_src[pos] = p.x;
    }
}

// One wave per node. lane = 32*p + c: half-wave p handles edge parity p,
// lane covers dims (2c, 2c+1) as one bfloat162 (4B) load. 4-deep unroll
// -> 8 row-loads in flight per wave. Output meanh bf16.
__global__ __launch_bounds__(256) void k_gather1(
    const unsigned short* __restrict__ xh,
    const int* __restrict__ row_ptr, const int* __restrict__ csr_src,
    unsigned int* __restrict__ meanh)
{
    int lane = threadIdx.x & 63;
    int w = threadIdx.x >> 6;
    int c = lane & 31;
    int p = lane >> 5;
    const unsigned int* xp = (const unsigned int*)xh;   // row = 32 uints

    for (int row = blockIdx.x * 4 + w; row < N_NODES; row += gridDim.x * 4) {
        int start = row_ptr[row];
        int end   = row_ptr[row + 1];
        int deg   = end - start;
        float x0 = 0.f, y0 = 0.f, x1 = 0.f, y1 = 0.f;
        float x2 = 0.f, y2 = 0.f, x3 = 0.f, y3 = 0.f;
        for (int eb = start; eb < end; eb += 64) {
            int nv = end - eb; if (nv > 64) nv = 64;
            int sid = (lane < nv) ? csr_src[eb + lane] : 0;
            if (nv == 64) {
                for (int j = 0; j < 64; j += 8) {
                    int s0 = __shfl(sid, j + 0 + p, 64);
                    int s1 = __shfl(sid, j + 2 + p, 64);
                    int s2 = __shfl(sid, j + 4 + p, 64);
                    int s3 = __shfl(sid, j + 6 + p, 64);
                    unsigned v0 = xp[s0 * 32 + c];
                    unsigned v1 = xp[s1 * 32 + c];
                    unsigned v2 = xp[s2 * 32 + c];
                    unsigned v3 = xp[s3 * 32 + c];
                    x0 += bflo(v0); y0 += bfhi(v0);
                    x1 += bflo(v1); y1 += bfhi(v1);
                    x2 += bflo(v2); y2 += bfhi(v2);
                    x3 += bflo(v3); y3 += bfhi(v3);
                }
            } else {
                for (int j = 0; j < nv; j += 2) {
                    int i = j + p;
                    int s = __shfl(sid, (i < 64) ? i : 0, 64);
                    if (i < nv) {
                        unsigned v = xp[s * 32 + c];
                        x0 += bflo(v); y0 += bfhi(v);
                    }
                }
            }
        }
        float fx = (x0 + x1) + (x2 + x3);
        float fy = (y0 + y1) + (y2 + y3);
        fx += __shfl_xor(fx, 32, 64);
        fy += __shfl_xor(fy, 32, 64);
        if (lane < 32) {
            float rdeg = 1.0f / fmaxf((float)deg, 1.0f);
            meanh[row * 32 + c] =
                (unsigned)f2bf(fx * rdeg) | ((unsigned)f2bf(fy * rdeg) << 16);
        }
    }
}

// MFMA bf16: wave computes 16 rows.
//  L1: [mean|x](16x128) @ W1cat^T -> h (+b1, relu)        16 MFMA 16x16x32
//  L2: h(16x64, via LDS relayout) @ W2cat^T -> hWl | hr    8 MFMA
// B-fragments pre-swizzled in LDS (1 ds_read_b128 per MFMA, conflict-free).
// A frag: lane holds A[m=lane&15][k = kc*32 + (lane>>4)*8 + j], j=0..7.
// C/D:    lane holds D[row=(lane>>4)*4+reg][col=lane&15] (verified m89).
__global__ __launch_bounds__(256) void k_gemm1(
    const unsigned short* __restrict__ xh, const unsigned short* __restrict__ meanh,
    const float* __restrict__ W1l, const float* __restrict__ W1r,
    const float* __restrict__ b1,
    const float* __restrict__ W2l, const float* __restrict__ W2r,
    unsigned short* __restrict__ hWlh, float* __restrict__ hr)
{
    __shared__ short sWB1[4 * 4 * 64 * 8];   // [kc][nt][lane][8]  16 KB
    __shared__ short sWB2[2 * 4 * 64 * 8];   // [kc2][nt][lane][8]  8 KB
    __shared__ short htile[4][16 * 72];      // per-wave h tile, stride 72 (16B-aligned)

    int tid = threadIdx.x;
    for (int e = tid; e < 1024; e += 256) {
        int kc = e >> 8, nt = (e >> 6) & 3, ln = e & 63;
        int cc = ln & 15, qd = ln >> 4;
        int n = nt * 16 + cc, k0 = kc * 32 + qd * 8;
        const float* sp = (k0 < 64) ? (W1l + n * 64 + k0) : (W1r + n * 64 + (k0 - 64));
        short* dp = sWB1 + e * 8;
        #pragma unroll
        for (int j = 0; j < 8; ++j) dp[j] = (short)f2bf(sp[j]);
    }
    for (int e = tid; e < 512; e += 256) {
        int kc = e >> 8, nt = (e >> 6) & 3, ln = e & 63;
        int cc = ln & 15, qd = ln >> 4;
        int n = nt * 16 + cc, k0 = kc * 32 + qd * 8;
        const float* sp = (n < 32) ? (W2l + n * 64 + k0) : (W2r + (n - 32) * 64 + k0);
        short* dp = sWB2 + e * 8;
        #pragma unroll
        for (int j = 0; j < 8; ++j) dp[j] = (short)f2bf(sp[j]);
    }
    __syncthreads();

    int lane = tid & 63, w = tid >> 6;
    int c = lane & 15, quad = lane >> 4;
    float bias[4];
    #pragma unroll
    for (int nt = 0; nt < 4; ++nt) bias[nt] = b1[nt * 16 + c];

    const bf16x8* B1 = (const bf16x8*)sWB1;
    const bf16x8* B2 = (const bf16x8*)sWB2;
    short* ht = htile[w];

    for (int r0 = blockIdx.x * 64 + w * 16; r0 < N_NODES; r0 += gridDim.x * 64) {
        int ra = r0 + c; if (ra > N_NODES - 1) ra = N_NODES - 1;
        const bf16x8* mrow = (const bf16x8*)((const unsigned short*)meanh + (size_t)ra * 64);
        const bf16x8* xrow = (const bf16x8*)(xh + (size_t)ra * 64);
        bf16x8 a0 = mrow[quad];       // kc=0: k in [0,32)
        bf16x8 a1 = mrow[4 + quad];   // kc=1: k in [32,64)
        bf16x8 a2 = xrow[quad];       // kc=2
        bf16x8 a3 = xrow[4 + quad];   // kc=3

        f32x4 acc[4];
        #pragma unroll
        for (int nt = 0; nt < 4; ++nt) acc[nt] = (f32x4){0.f, 0.f, 0.f, 0.f};
        #pragma unroll
        for (int nt = 0; nt < 4; ++nt)
            acc[nt] = __builtin_amdgcn_mfma_f32_16x16x32_bf16(a0, B1[(0 * 4 + nt) * 64 + lane], acc[nt], 0, 0, 0);
        #pragma unroll
        for (int nt = 0; nt < 4; ++nt)
            acc[nt] = __builtin_amdgcn_mfma_f32_16x16x32_bf16(a1, B1[(1 * 4 + nt) * 64 + lane], acc[nt], 0, 0, 0);
        #pragma unroll
        for (int nt = 0; nt < 4; ++nt)
            acc[nt] = __builtin_amdgcn_mfma_f32_16x16x32_bf16(a2, B1[(2 * 4 + nt) * 64 + lane], acc[nt], 0, 0, 0);
        #pragma unroll
        for (int nt = 0; nt < 4; ++nt)
            acc[nt] = __builtin_amdgcn_mfma_f32_16x16x32_bf16(a3, B1[(3 * 4 + nt) * 64 + lane], acc[nt], 0, 0, 0);

        #pragma unroll
        for (int nt = 0; nt < 4; ++nt) {
            #pragma unroll
            for (int reg = 0; reg < 4; ++reg) {
                float hv = fmaxf(acc[nt][reg] + bias[nt], 0.0f);
                ht[(quad * 4 + reg) * 72 + nt * 16 + c] = (short)f2bf(hv);
            }
        }
        bf16x8 h0 = *(const bf16x8*)(ht + c * 72 + 0  + quad * 8);
        bf16x8 h1 = *(const bf16x8*)(ht + c * 72 + 32 + quad * 8);

        f32x4 acc2[4];
        #pragma unroll
        for (int nt = 0; nt < 4; ++nt) acc2[nt] = (f32x4){0.f, 0.f, 0.f, 0.f};
        #pragma unroll
        for (int nt = 0; nt < 4; ++nt)
            acc2[nt] = __builtin_amdgcn_mfma_f32_16x16x32_bf16(h0, B2[(0 * 4 + nt) * 64 + lane], acc2[nt], 0, 0, 0);
        #pragma unroll
        for (int nt = 0; nt < 4; ++nt)
            acc2[nt] = __builtin_amdgcn_mfma_f32_16x16x32_bf16(h1, B2[(1 * 4 + nt) * 64 + lane], acc2[nt], 0, 0, 0);

        #pragma unroll
        for (int nt = 0; nt < 4; ++nt) {
            #pragma unroll
            for (int reg = 0; reg < 4; ++reg) {
                int row = r0 + quad * 4 + reg;
                if (row < N_NODES) {
                    if (nt < 2) hWlh[(size_t)row * 32 + nt * 16 + c] = f2bf(acc2[nt][reg]);
                    else        hr[(size_t)row * 32 + (nt - 2) * 16 + c] = acc2[nt][reg];
                }
            }
        }
    }
}

// One wave per node. lane = 16*q + c: quarter q handles edges =q mod 4,
// lane covers dims (2c,2c+1) of bf16 hWl row (64B). 4-deep unroll ->
// 16 row-loads in flight per wave. Epilogue: +hr +b2 -> out.
__global__ __launch_bounds__(256) void k_l2(
    const unsigned short* __restrict__ hWlh, const float* __restrict__ hr,
    const int* __restrict__ row_ptr, const int* __restrict__ csr_src,
    const float* __restrict__ b2, float* __restrict__ out)
{
    int lane = threadIdx.x & 63;
    int w = threadIdx.x >> 6;
    int c = lane & 15;
    int q = lane >> 4;
    const unsigned int* hp = (const unsigned int*)hWlh;   // row = 16 uints
    float2 b2v = ((const float2*)b2)[c];

    for (int row = blockIdx.x * 4 + w; row < N_NODES; row += gridDim.x * 4) {
        int start = row_ptr[row];
        int end   = row_ptr[row + 1];
        int deg = end - start;
        float x0 = 0.f, y0 = 0.f, x1 = 0.f, y1 = 0.f;
        float x2 = 0.f, y2 = 0.f, x3 = 0.f, y3 = 0.f;
        for (int eb = start; eb < end; eb += 64) {
            int nv = end - eb; if (nv > 64) nv = 64;
            int sid = (lane < nv) ? csr_src[eb + lane] : 0;
            if (nv == 64) {
                for (int j = 0; j < 64; j += 16) {
                    int s0 = __shfl(sid, j + 0  + q, 64);
                    int s1 = __shfl(sid, j + 4  + q, 64);
                    int s2 = __shfl(sid, j + 8  + q, 64);
                    int s3 = __shfl(sid, j + 12 + q, 64);
                    unsigned v0 = hp[s0 * 16 + c];
                    unsigned v1 = hp[s1 * 16 + c];
                    unsigned v2 = hp[s2 * 16 + c];
                    unsigned v3 = hp[s3 * 16 + c];
                    x0 += bflo(v0); y0 += bfhi(v0);
                    x1 += bflo(v1); y1 += bfhi(v1);
                    x2 += bflo(v2); y2 += bfhi(v2);
                    x3 += bflo(v3); y3 += bfhi(v3);
                }
            } else {
                for (int j = 0; j < nv; j += 4) {
                    int i = j + q;
                    int s = __shfl(sid, (i < 64) ? i : 0, 64);
                    if (i < nv) {
                        unsigned v = hp[s * 16 + c];
                        x0 += bflo(v); y0 += bfhi(v);
                    }
                }
            }
        }
        float fx = (x0 + x1) + (x2 + x3);
        float fy = (y0 + y1) + (y2 + y3);
        fx += __shfl_xor(fx, 16, 64);
        fy += __shfl_xor(fy, 16, 64);
        fx += __shfl_xor(fx, 32, 64);
        fy += __shfl_xor(fy, 32, 64);
        if (lane < 16) {
            float rdeg = 1.0f / fmaxf((float)deg, 1.0f);
            float2 hv = ((const float2*)hr)[(size_t)row * 16 + c];
            float2 o;
            o.x = fmaf(fx, rdeg, hv.x + b2v.x);
            o.y = fmaf(fy, rdeg, hv.y + b2v.y);
            ((float2*)out)[(size_t)row * 16 + c] = o;
        }
    }
}

extern "C" void kernel_launch(void* const* d_in, const int* in_sizes, int n_in,
                              void* d_out, int out_size, void* d_ws, size_t ws_size,
                              hipStream_t stream) {
    const float* x   = (const float*)d_in[0];
    const int*   ei  = (const int*)d_in[1];
    const float* W1l = (const float*)d_in[2];
    const float* W1r = (const float*)d_in[3];
    const float* b1  = (const float*)d_in[4];
    const float* W2l = (const float*)d_in[5];
    const float* W2r = (const float*)d_in[6];
    const float* b2  = (const float*)d_in[7];
    float* out = (float*)d_out;

    const int* src = ei;
    const int* dst = ei + N_EDGES;

    char* w = (char*)d_ws;
    int* cnt     = (int*)w;   w += sizeof(int) * N_NODES;
    int* row_ptr = (int*)w;   w += sizeof(int) * (N_NODES + 4);
    int* part    = (int*)w;   w += sizeof(int) * 128;
    int* base    = (int*)w;   w += sizeof(int) * 128;
    int* bcur    = (int*)w;   w += sizeof(int) * 256;
    int* csr_src = (int*)w;   w += sizeof(int) * N_EDGES;
    int2* ebuf   = (int2*)w;  w += sizeof(int2) * N_EDGES;
    unsigned short* xh    = (unsigned short*)w; w += sizeof(short) * (size_t)N_NODES * 64;
    unsigned int*   meanh = (unsigned int*)w;   w += sizeof(int)   * (size_t)N_NODES * 32;
    unsigned short* hWlh  = (unsigned short*)w; w += sizeof(short) * (size_t)N_NODES * 32;
    float*          hr    = (float*)w;          /* + 12.8 MB; total ~61 MB */

    hipMemsetAsync(cnt, 0, sizeof(int) * N_NODES, stream);

    k_tobf16<<<(N_NODES * 64 / 4 + 255) / 256, 256, 0, stream>>>(x, xh);
    k_hist<<<(N_EDGES + 255) / 256, 256, 0, stream>>>(dst, cnt);
    k_scan_a<<<SCAN_NB, 256, 0, stream>>>(cnt, part);
    k_scan_b<<<1, 128, 0, stream>>>(part, base, row_ptr);
    k_scan_c<<<SCAN_NB, 256, 0, stream>>>(cnt, base, row_ptr, bcur);
    k_pha<<<PHA_NB, 256, 0, stream>>>(src, dst, bcur, ebuf);
    k_phb<<<BUCKETS, 256, 0, stream>>>(ebuf, row_ptr, csr_src);
    k_gather1<<<2048, 256, 0, stream>>>(xh, row_ptr, csr_src, meanh);
    k_gemm1<<<(N_NODES + 63) / 64, 256, 0, stream>>>(
        xh, (const unsigned short*)meanh, W1l, W1r, b1, W2l, W2r, hWlh, hr);
    k_l2<<<2048, 256, 0, stream>>>(hWlh, hr, row_ptr, csr_src, b2, out);
}